// Round 5
// baseline (333.445 us; speedup 1.0000x reference)
//
#include <hip/hip_runtime.h>
#include <stdint.h>

// Problem constants (from reference setup_inputs)
#define B_DIM   16384
#define IN_DIM  2048
#define OUT_DIM 2048
#define BN_EPS  1e-5f

typedef int    i32x4  __attribute__((ext_vector_type(4)));
typedef int    i32x16 __attribute__((ext_vector_type(16)));
typedef unsigned short u16x4 __attribute__((ext_vector_type(4)));

// ---------- helpers ----------

__device__ __forceinline__ unsigned short f2bf_rne(float f) {
    unsigned u = __builtin_bit_cast(unsigned, f);
    return (unsigned short)((u + 0x7fffu + ((u >> 16) & 1u)) >> 16);
}
__device__ __forceinline__ float bf2f(unsigned short h) {
    unsigned u = ((unsigned)h) << 16;
    return __builtin_bit_cast(float, u);
}

// async global->LDS, 16B per lane. LDS dst = wave-uniform base + lane*16.
__device__ __forceinline__ void gl_lds16(const void* g, void* l) {
    __builtin_amdgcn_global_load_lds(
        (const __attribute__((address_space(1))) unsigned int*)g,
        (__attribute__((address_space(3))) unsigned int*)l,
        16, 0, 0);
}

__device__ __forceinline__ int pack4(float a, float b, float c, float d, float inv) {
    int q0 = (int)rintf(a * inv) & 255;
    int q1 = (int)rintf(b * inv) & 255;
    int q2 = (int)rintf(c * inv) & 255;
    int q3 = (int)rintf(d * inv) & 255;
    return q0 | (q1 << 8) | (q2 << 16) | (q3 << 24);
}

// ---------- kernel 1: x fp32 -> i8 with per-row scale ----------
__global__ __launch_bounds__(256) void quantize_x_kernel(
        const float4* __restrict__ x4, int* __restrict__ xq,
        float* __restrict__ scales) {
    __shared__ float wmax[4];
    const int row = blockIdx.x;
    const int t = threadIdx.x;
    const float4* xr = x4 + (size_t)row * 512;
    float4 a = xr[t];          // 16B coalesced
    float4 b = xr[t + 256];
    float m = fmaxf(fmaxf(fabsf(a.x), fabsf(a.y)), fmaxf(fabsf(a.z), fabsf(a.w)));
    m = fmaxf(m, fmaxf(fmaxf(fabsf(b.x), fabsf(b.y)), fmaxf(fabsf(b.z), fabsf(b.w))));
#pragma unroll
    for (int off = 32; off >= 1; off >>= 1) m = fmaxf(m, __shfl_xor(m, off));
    if ((t & 63) == 0) wmax[t >> 6] = m;
    __syncthreads();
    m = fmaxf(fmaxf(wmax[0], wmax[1]), fmaxf(wmax[2], wmax[3]));
    m = fmaxf(m, 1e-20f);                 // guard all-zero row
    const float inv = 127.0f / m;
    if (t == 0) scales[row] = m * (1.0f / 127.0f);
    int* xo = xq + (size_t)row * 512;
    xo[t]       = pack4(a.x, a.y, a.z, a.w, inv);   // 4B coalesced
    xo[t + 256] = pack4(b.x, b.y, b.z, b.w, inv);
}

// ---------- kernel 2: w fp32 -> sign i8 (+1/-1); also zero stat accums ----------
__global__ __launch_bounds__(256) void convert_w_kernel(
        const float4* __restrict__ w, int* __restrict__ wq,
        float4* __restrict__ stats /* colsum[2048]+colsumsq[2048] */) {
    int id = blockIdx.x * 256 + threadIdx.x;       // exact: 4096 blocks
    if (id < 1024) stats[id] = make_float4(0.f, 0.f, 0.f, 0.f);
    float4 a = w[id];
    int b0 = (a.x < 0.f) ? 0xFF : 0x01;
    int b1 = (a.y < 0.f) ? 0xFF : 0x01;
    int b2 = (a.z < 0.f) ? 0xFF : 0x01;
    int b3 = (a.w < 0.f) ? 0xFF : 0x01;
    wq[id] = b0 | (b1 << 8) | (b2 << 16) | (b3 << 24);
}

// ---------- kernel 3: i8 GEMM (NT) + column sum/sumsq epilogue ----------
// 128x128 tile, BK=128 bytes, 32x32x32 i8 MFMA, 4 waves 2x2, each wave 64x64
// as 2x2 of 32x32 tiles. LDS rows are 64B; columns XOR-swizzled by
// f(row) = ((row ^ row>>2) & 3) << 4 so fragment ds_read_b128 hits all 8
// 16B-bank-groups (was 8-way conflicted in R3/R4: 8.39M SQ_LDS_BANK_CONFLICT).
// Swizzle is applied to the *global source column* at staging so the LDS
// destination stays lane-contiguous (global_load_lds requirement).
__global__ __launch_bounds__(256, 2) void gemm_bn_kernel(
        const char* __restrict__ A, const char* __restrict__ Bw,
        const float* __restrict__ scales,
        unsigned short* __restrict__ Yb,
        float* __restrict__ colsum, float* __restrict__ colsumsq) {
    __shared__ char sA[2 * 128 * 64];   // [slab][row][64B]
    __shared__ char sB[2 * 128 * 64];

    const int tid  = threadIdx.x;
    const int wave = tid >> 6;
    const int lane = tid & 63;
    const int wm = wave >> 1;         // wave row (0..1) -> 64 rows of M
    const int wn = wave & 1;          // wave col (0..1) -> 64 cols of N
    const int r  = lane & 31;         // row/col within 32
    const int hw = lane >> 5;         // half-wave (k-split)
    const int swz = (r ^ (r >> 2)) & 3;

    // XCD swizzle: contiguous logical tiles per XCD -> A-tile L2 locality.
    const int b  = blockIdx.x;                 // 0..2047
    const int lb = (b & 7) * 256 + (b >> 3);   // bijection on [0,2048)
    const int bm = (lb >> 4) * 128;            // 128 M tiles
    const int bn = (lb & 15) * 128;            // 16 N tiles

    // staging: 32 chunks/iter (A:16, B:16), 8 per wave; chunk = 16 rows x 16B
    // of one k-half slab. Global source column is swizzled per destination row.
    const int srow = lane >> 2;                // 0..15
    const int fsw  = ((srow ^ (srow >> 2)) & 3) << 4;
    const int scol = (((lane & 3) << 4)) ^ fsw; // swizzled source col in [0,64)
    const char* gp[8];
    char* lp[8];
#pragma unroll
    for (int q = 0; q < 8; ++q) {
        int g    = wave * 8 + q;
        int isB  = g >> 4;
        int slab = (g >> 3) & 1;
        int c    = g & 7;
        const char* basep = isB ? Bw : A;
        int tileoff       = isB ? bn : bm;
        gp[q] = basep + (size_t)(tileoff + c * 16 + srow) * IN_DIM
                      + slab * 64 + scol;
        char* sbase = isB ? sB : sA;
        lp[q] = sbase + slab * 8192 + c * 1024 + lane * 16;
    }

    // fragment row byte-offsets (col added per k-subiter with swizzle)
    const int arow = (wm * 64 + r) * 64;
    const int brow = (wn * 64 + r) * 64;

    i32x16 acc[2][2];
#pragma unroll
    for (int i = 0; i < 2; ++i)
#pragma unroll
        for (int j = 0; j < 2; ++j)
#pragma unroll
            for (int e = 0; e < 16; ++e) acc[i][j][e] = 0;

    for (int k0 = 0; k0 < IN_DIM; k0 += 128) {
        __syncthreads();                       // previous iter's ds_reads done
#pragma unroll
        for (int q = 0; q < 8; ++q)
            gl_lds16(gp[q] + k0, lp[q]);
        __syncthreads();                       // staging complete

#pragma unroll
        for (int ks = 0; ks < 4; ++ks) {       // K=32 each
            const int slab = (ks >> 1) * 8192;
            const int col  = ((((ks & 1) << 1) | hw) ^ swz) << 4;
            i32x4 a0 = *(const i32x4*)(sA + slab + arow + col);
            i32x4 a1 = *(const i32x4*)(sA + slab + arow + 2048 + col);
            i32x4 b0 = *(const i32x4*)(sB + slab + brow + col);
            i32x4 b1 = *(const i32x4*)(sB + slab + brow + 2048 + col);
            acc[0][0] = __builtin_amdgcn_mfma_i32_32x32x32_i8(a0, b0, acc[0][0], 0, 0, 0);
            acc[0][1] = __builtin_amdgcn_mfma_i32_32x32x32_i8(a0, b1, acc[0][1], 0, 0, 0);
            acc[1][0] = __builtin_amdgcn_mfma_i32_32x32x32_i8(a1, b0, acc[1][0], 0, 0, 0);
            acc[1][1] = __builtin_amdgcn_mfma_i32_32x32x32_i8(a1, b1, acc[1][1], 0, 0, 0);
        }
    }

    // epilogue: y = scales[m]*acc. 32x32 C/D: col = lane&31,
    // row = (reg&3) + 8*(reg>>2) + 4*hw.
    float colS[2] = {0.f, 0.f}, colQ[2] = {0.f, 0.f};
#pragma unroll
    for (int i = 0; i < 2; ++i) {
        const int row0 = bm + wm * 64 + i * 32 + hw * 4;
#pragma unroll
        for (int reg = 0; reg < 16; ++reg) {
            const int row = row0 + (reg & 3) + ((reg >> 2) << 3);
            const float sc = scales[row];
            size_t base = (size_t)row * OUT_DIM + bn + wn * 64 + r;
#pragma unroll
            for (int j = 0; j < 2; ++j) {
                float v = (float)acc[i][j][reg] * sc;
                Yb[base + j * 32] = f2bf_rne(v);
                colS[j] += v;
                colQ[j] += v * v;
            }
        }
    }
    // combine the two half-waves (same columns), then one atomic per column
#pragma unroll
    for (int j = 0; j < 2; ++j) {
        float s = colS[j], q = colQ[j];
        s += __shfl_xor(s, 32);
        q += __shfl_xor(q, 32);
        if (hw == 0) {
            int col = bn + wn * 64 + j * 32 + r;
            atomicAdd(&colsum[col], s);
            atomicAdd(&colsumsq[col], q);
        }
    }
}

// ---------- kernel 4: finalize BN params ----------
__global__ __launch_bounds__(256) void finalize_kernel(
        const float* __restrict__ colsum, const float* __restrict__ colsumsq,
        const float* __restrict__ gamma, const float* __restrict__ beta,
        float* __restrict__ scale, float* __restrict__ bias) {
    int n = blockIdx.x * 256 + threadIdx.x;
    if (n < OUT_DIM) {
        const float inv = 1.f / (float)B_DIM;
        float mean = colsum[n] * inv;
        float var  = colsumsq[n] * inv - mean * mean;
        float sc   = gamma[n] * rsqrtf(var + BN_EPS);
        scale[n] = sc;
        bias[n]  = beta[n] - mean * sc;
    }
}

// ---------- kernel 5: bf16 Y -> affine+ReLU -> fp32 out. 8 elems/thread ----------
__global__ __launch_bounds__(256) void bn_relu_bf16_kernel(
        const u16x4* __restrict__ yb, float4* __restrict__ out,
        const float4* __restrict__ scale4, const float4* __restrict__ bias4) {
    int base = blockIdx.x * 512 + threadIdx.x;   // block covers 512 f4-groups
#pragma unroll
    for (int p = 0; p < 2; ++p) {
        int id = base + p * 256;                 // coalesced both passes
        int c4 = id & (OUT_DIM / 4 - 1);         // column group (2048%4==0)
        u16x4 h = yb[id];                        // 8B coalesced read
        float4 s = scale4[c4];
        float4 bb = bias4[c4];
        float4 v;
        v.x = fmaxf(fmaf(bf2f(h[0]), s.x, bb.x), 0.f);
        v.y = fmaxf(fmaf(bf2f(h[1]), s.y, bb.y), 0.f);
        v.z = fmaxf(fmaf(bf2f(h[2]), s.z, bb.z), 0.f);
        v.w = fmaxf(fmaf(bf2f(h[3]), s.w, bb.w), 0.f);
        out[id] = v;                             // 16B coalesced write
    }
}

// ---------- launch ----------
extern "C" void kernel_launch(void* const* d_in, const int* in_sizes, int n_in,
                              void* d_out, int out_size, void* d_ws, size_t ws_size,
                              hipStream_t stream) {
    const float* x     = (const float*)d_in[0];   // [16384, 2048]
    const float* w     = (const float*)d_in[1];   // [2048, 2048]
    const float* gamma = (const float*)d_in[2];   // [2048]
    const float* beta  = (const float*)d_in[3];   // [2048]
    float* out = (float*)d_out;                   // [16384, 2048]

    char* ws = (char*)d_ws;
    // ws layout: xq 32MB | wq 4MB | yb 64MB | stats 32KB | scales 64KB
    const size_t XQ_OFF = 0;
    const size_t WQ_OFF = XQ_OFF + (size_t)B_DIM * IN_DIM;          // 33,554,432
    const size_t YB_OFF = WQ_OFF + (size_t)OUT_DIM * IN_DIM;        // 37,748,736
    const size_t ST_OFF = YB_OFF + (size_t)B_DIM * OUT_DIM * 2;     // 104,857,600
    const size_t SC_OFF = ST_OFF + 8192 * 4;                        // 104,890,368

    char* xq = ws + XQ_OFF;
    char* wq = ws + WQ_OFF;
    unsigned short* yb = (unsigned short*)(ws + YB_OFF);
    float* colsum   = (float*)(ws + ST_OFF);
    float* colsumsq = colsum + 2048;
    float* scale    = colsum + 4096;
    float* bias     = colsum + 6144;
    float* scales   = (float*)(ws + SC_OFF);      // per-row x scales [16384]

    quantize_x_kernel<<<B_DIM, 256, 0, stream>>>(
        (const float4*)x, (int*)xq, scales);
    convert_w_kernel<<<4096, 256, 0, stream>>>(
        (const float4*)w, (int*)wq, (float4*)colsum);
    gemm_bn_kernel<<<2048, 256, 0, stream>>>(
        xq, wq, scales, yb, colsum, colsumsq);
    finalize_kernel<<<8, 256, 0, stream>>>(
        colsum, colsumsq, gamma, beta, scale, bias);
    bn_relu_bf16_kernel<<<16384, 256, 0, stream>>>(
        (const u16x4*)yb, (float4*)out, (const float4*)scale,
        (const float4*)bias);
}